// Round 13
// baseline (409.427 us; speedup 1.0000x reference)
//
#include <hip/hip_runtime.h>

#define NN 100000
#define NE 1600000
#define NB ((NN + 255) / 256)
#define TPW 8                      // 16-edge tiles per wave in k_edge_mfma
#define HB ((NE + 255) / 256)      // hist blocks = 6250
#define PB ((4096 + NN * 16 + 255) / 256)  // prep blocks

typedef unsigned int uint32;
typedef float f32x4 __attribute__((ext_vector_type(4)));
typedef short bf16x8 __attribute__((ext_vector_type(8)));

__device__ __forceinline__ float bflo(uint32 u) { return __uint_as_float(u << 16); }
__device__ __forceinline__ float bfhi(uint32 u) { return __uint_as_float(u & 0xffff0000u); }
__device__ __forceinline__ uint32 bfbits(float v) { return (__float_as_uint(v) + 0x8000u) >> 16; }
__device__ __forceinline__ uint32 pack2(float a, float b) { return bfbits(a) | (bfbits(b) << 16); }

// channel permutation: sigma(c) swaps cc (bits 5:4) and qq (bits 3:2) fields
__device__ __forceinline__ int sigma_ch(int c) {
    return (((c >> 2) & 3) << 4) + (((c >> 4) & 3) << 2) + (c & 3);
}

// ---------------- fused: histogram+rank  ||  Wc/bc/wpack/xbw prep ----------------
__global__ __launch_bounds__(256) void k_hist_prep(
    const int* __restrict__ ei, int* __restrict__ deg, int* __restrict__ rank,
    const float* __restrict__ W1b, const float* __restrict__ b1b,
    const float* __restrict__ W2a, const float* __restrict__ W1a, const float* __restrict__ x,
    float* __restrict__ Wc, float* __restrict__ bc,
    uint4* __restrict__ wpack, uint32* __restrict__ xbw, int perm)
{
    int b = blockIdx.x;
    if (b < HB) {
        int e = b * 256 + threadIdx.x;
        if (e < NE) rank[e] = atomicAdd(&deg[ei[e]], 1);
        return;
    }
    int idx = (b - HB) * 256 + threadIdx.x;
    if (idx < 4096) {
        int r = idx >> 6, c = idx & 63;
        float a = 0.f;
        for (int k = 0; k < 64; ++k) a += W1b[r * 64 + k] * W2a[(32 + k) * 64 + c];
        int rs = perm ? sigma_ch(r) : r;
        Wc[rs * 64 + c] = a;
        if (idx < 64) {
            float bacc = 0.f;
            for (int k = 0; k < 64; ++k) bacc += b1b[k] * W2a[(32 + k) * 64 + idx];
            bc[idx] = bacc;
        }
        if (idx < 512) {
            int table = idx >> 8;
            int cc = (idx >> 6) & 3;
            int lane = idx & 63;
            int qq = lane >> 4, en = lane & 15;
            int ch = cc * 16 + en;
            uint32 w[4];
            #pragma unroll
            for (int j = 0; j < 4; ++j) {
                int row0 = (table ? 0 : 32) + qq * 8 + j * 2;
                w[j] = pack2(W1a[row0 * 64 + ch], W1a[(row0 + 1) * 64 + ch]);
            }
            wpack[idx] = make_uint4(w[0], w[1], w[2], w[3]);
        }
    }
    int xi = idx - 4096;
    if (xi >= 0 && xi < NN * 16) {
        float2 v = *(const float2*)(x + (size_t)2 * xi);
        xbw[xi] = pack2(v.x, v.y);
    }
}

__global__ __launch_bounds__(256) void k_scan1(const int* __restrict__ deg, int* __restrict__ offs,
                                               int* __restrict__ bsums, int n) {
    __shared__ int s[256];
    int tid = threadIdx.x;
    int i = blockIdx.x * 256 + tid;
    int v = (i < n) ? deg[i] : 0;
    int acc = v;
    s[tid] = acc;
    __syncthreads();
    #pragma unroll
    for (int off = 1; off < 256; off <<= 1) {
        int t = (tid >= off) ? s[tid - off] : 0;
        __syncthreads();
        acc += t;
        s[tid] = acc;
        __syncthreads();
    }
    if (i < n) offs[i] = acc - v;
    if (tid == 255) bsums[blockIdx.x] = acc;
}

__global__ __launch_bounds__(512) void k_scan2(int* __restrict__ bsums, int nb) {
    __shared__ int s[512];
    int tid = threadIdx.x;
    int v = (tid < nb) ? bsums[tid] : 0;
    int acc = v;
    s[tid] = acc;
    __syncthreads();
    #pragma unroll
    for (int off = 1; off < 512; off <<= 1) {
        int t = (tid >= off) ? s[tid - off] : 0;
        __syncthreads();
        acc += t;
        s[tid] = acc;
        __syncthreads();
    }
    bsums[tid] = acc - v;
}

// ---------------- MFMA edge kernel: g[slot(e)] = bf16(relu(b1a + x[col]@W1a_top + ea@W1a_bot)) ----------------
// slot computed inline: rank[e] + offs[row] + bsums[row>>8]  (no k_pos pass)
// A = wpack fragments (channels on M), B = ea row / xb row (edge on col), C init = b1a.
// D/C: lane(qq,en) -> col(edge)=en, channel cc*16+qq*4+r; write = sigma word order (matches Wc).
__global__ __launch_bounds__(256) void k_edge_mfma(
    const int* __restrict__ ei, const float* __restrict__ ea, const uint32* __restrict__ xbw,
    const uint4* __restrict__ wpack, const float* __restrict__ b1a,
    const int* __restrict__ rank, const int* __restrict__ offs, const int* __restrict__ bsums,
    uint32* __restrict__ g)
{
    int lane = threadIdx.x & 63;
    int wave = threadIdx.x >> 6;
    int en = lane & 15;
    int qq = lane >> 4;

    union U { uint4 u; bf16x8 v; };
    U wB[4], wA[4];
    #pragma unroll
    for (int cc = 0; cc < 4; ++cc) {
        wB[cc].u = wpack[cc * 64 + lane];
        wA[cc].u = wpack[256 + cc * 64 + lane];
    }
    f32x4 binit[4];
    #pragma unroll
    for (int cc = 0; cc < 4; ++cc) {
        float4 b = *(const float4*)(b1a + cc * 16 + qq * 4);
        binit[cc] = (f32x4){b.x, b.y, b.z, b.w};
    }

    int base = blockIdx.x * (64 * TPW) + wave * (16 * TPW);

    // ---- prologue: tile 0 fully resolved, tile 1 level-1 issued ----
    int e0 = base + en;
    int r0 = ei[e0];
    int c0 = ei[NE + e0];
    int k0 = rank[e0];
    float4 f0a = *(const float4*)(ea + (size_t)e0 * 32 + qq * 8);
    float4 f0b = *(const float4*)(ea + (size_t)e0 * 32 + qq * 8 + 4);
    int p0 = k0 + offs[r0] + bsums[r0 >> 8];

    int e1 = base + 16 + en;
    int r1 = ei[e1];
    int c1 = ei[NE + e1];
    int k1 = rank[e1];
    float4 f1a = *(const float4*)(ea + (size_t)e1 * 32 + qq * 8);
    float4 f1b = *(const float4*)(ea + (size_t)e1 * 32 + qq * 8 + 4);

    uint4 xv0 = *(const uint4*)(xbw + (size_t)c0 * 16 + qq * 4);

    #pragma unroll 1
    for (int t = 0; t < TPW; ++t) {
        // prefetch tile t+2 (clamped; clamped values never used in compute)
        int e2 = base + (t + 2) * 16 + en;
        if (e2 > NE - 1) e2 = NE - 1;
        int r2 = ei[e2];
        int c2 = ei[NE + e2];
        int k2 = rank[e2];
        float4 f2a = *(const float4*)(ea + (size_t)e2 * 32 + qq * 8);
        float4 f2b = *(const float4*)(ea + (size_t)e2 * 32 + qq * 8 + 4);
        // resolve tile t+1: slot + xb gather
        int p1 = k1 + offs[r1] + bsums[r1 >> 8];
        uint4 xv1 = *(const uint4*)(xbw + (size_t)c1 * 16 + qq * 4);

        // ---- compute tile t ----
        U bea, bx;
        bea.u.x = pack2(f0a.x, f0a.y);
        bea.u.y = pack2(f0a.z, f0a.w);
        bea.u.z = pack2(f0b.x, f0b.y);
        bea.u.w = pack2(f0b.z, f0b.w);
        bx.u = xv0;

        f32x4 acc[4];
        #pragma unroll
        for (int cc = 0; cc < 4; ++cc) acc[cc] = binit[cc];
        #pragma unroll
        for (int cc = 0; cc < 4; ++cc)
            acc[cc] = __builtin_amdgcn_mfma_f32_16x16x32_bf16(wB[cc].v, bea.v, acc[cc], 0, 0, 0);
        #pragma unroll
        for (int cc = 0; cc < 4; ++cc)
            acc[cc] = __builtin_amdgcn_mfma_f32_16x16x32_bf16(wA[cc].v, bx.v, acc[cc], 0, 0, 0);

        uint4 o0, o1;
        o0.x = pack2(fmaxf(acc[0][0], 0.f), fmaxf(acc[0][1], 0.f));
        o0.y = pack2(fmaxf(acc[0][2], 0.f), fmaxf(acc[0][3], 0.f));
        o0.z = pack2(fmaxf(acc[1][0], 0.f), fmaxf(acc[1][1], 0.f));
        o0.w = pack2(fmaxf(acc[1][2], 0.f), fmaxf(acc[1][3], 0.f));
        o1.x = pack2(fmaxf(acc[2][0], 0.f), fmaxf(acc[2][1], 0.f));
        o1.y = pack2(fmaxf(acc[2][2], 0.f), fmaxf(acc[2][3], 0.f));
        o1.z = pack2(fmaxf(acc[3][0], 0.f), fmaxf(acc[3][1], 0.f));
        o1.w = pack2(fmaxf(acc[3][2], 0.f), fmaxf(acc[3][3], 0.f));
        uint4* gp = (uint4*)(g + (size_t)p0 * 32 + qq * 8);
        gp[0] = o0;
        gp[1] = o1;

        // ---- rotate (all names static) ----
        p0 = p1; f0a = f1a; f0b = f1b; xv0 = xv1;
        r1 = r2; c1 = c2; k1 = k2; f1a = f2a; f1b = f2b;
    }
}

// ---------------- fused segment-sum + node MLP: wave per node, grid-stride ----------------
// seg: identical access pattern to proven k_seg_c. MLP: lane j owns channel j; S broadcast
// via __shfl from quarter-0 lanes; W2b phase split in halves + shfl_xor(32). No LDS exchange.
#define SN_BLOCKS 2048
__global__ __launch_bounds__(256) void k_segnode(
    const int* __restrict__ deg, const int* __restrict__ offs, const int* __restrict__ bsums,
    const uint32* __restrict__ g, const float* __restrict__ x,
    const float* __restrict__ Wc, const float* __restrict__ bc,
    const float* __restrict__ W2a, const float* __restrict__ b2a,
    const float* __restrict__ W2b, const float* __restrict__ b2b,
    float* __restrict__ out)
{
    __shared__ float sWc[64 * 64];     // sigma rows
    __shared__ float sW2ax[32 * 64];   // W2a rows 0..31 (natural)
    __shared__ float sW2b[64 * 32];
    __shared__ float sbc2[64];
    __shared__ float sb2[64];
    __shared__ float sb2b_[32];
    for (int t = threadIdx.x; t < 64 * 64; t += 256) sWc[t] = Wc[t];
    for (int t = threadIdx.x; t < 32 * 64; t += 256) sW2ax[t] = W2a[t];
    for (int t = threadIdx.x; t < 64 * 32; t += 256) sW2b[t] = W2b[t];
    if (threadIdx.x < 64) {
        sbc2[threadIdx.x] = bc[threadIdx.x] + b2a[threadIdx.x];
        sb2[threadIdx.x] = b2a[threadIdx.x];
    }
    if (threadIdx.x < 32) sb2b_[threadIdx.x] = b2b[threadIdx.x];
    __syncthreads();

    int lane = threadIdx.x & 63;
    int wave = threadIdx.x >> 6;
    int quarter = lane >> 4;
    int wi = lane & 15;

    for (int node = blockIdx.x * 4 + wave; node < NN; node += SN_BLOCKS * 4) {
        int d = deg[node];
        size_t start = (size_t)(offs[node] + bsums[node >> 8]);

        // ---- segment sum (4 rows/iter) ----
        float4 S = {0.f, 0.f, 0.f, 0.f};
        int r = quarter;
        for (; r + 4 < d; r += 8) {
            uint2 u1 = *(const uint2*)(g + (start + r) * 32 + wi * 2);
            uint2 u2 = *(const uint2*)(g + (start + r + 4) * 32 + wi * 2);
            S.x += bflo(u1.x) + bflo(u2.x);
            S.y += bfhi(u1.x) + bfhi(u2.x);
            S.z += bflo(u1.y) + bflo(u2.y);
            S.w += bfhi(u1.y) + bfhi(u2.y);
        }
        if (r < d) {
            uint2 u = *(const uint2*)(g + (start + r) * 32 + wi * 2);
            S.x += bflo(u.x); S.y += bfhi(u.x); S.z += bflo(u.y); S.w += bfhi(u.y);
        }
        S.x += __shfl_xor(S.x, 16); S.y += __shfl_xor(S.y, 16);
        S.z += __shfl_xor(S.z, 16); S.w += __shfl_xor(S.w, 16);
        S.x += __shfl_xor(S.x, 32); S.y += __shfl_xor(S.y, 32);
        S.z += __shfl_xor(S.z, 32); S.w += __shfl_xor(S.w, 32);
        // now lanes 0..15 (quarter==0) hold S for sigma positions wi*4..wi*4+3
        float inv = (d > 0) ? 1.f / (float)d : 0.f;
        S.x *= inv; S.y *= inv; S.z *= inv; S.w *= inv;

        // ---- node MLP: lane j = channel j ----
        int j = lane;
        float h = (d > 0) ? sbc2[j] : sb2[j];
        // h += mean @ Wc   (S[k] lives on lane k>>2, component k&3)
        #pragma unroll
        for (int k = 0; k < 64; k += 4) {
            float s0 = __shfl(S.x, k >> 2);
            float s1 = __shfl(S.y, k >> 2);
            float s2 = __shfl(S.z, k >> 2);
            float s3 = __shfl(S.w, k >> 2);
            h += s0 * sWc[(k + 0) * 64 + j];
            h += s1 * sWc[(k + 1) * 64 + j];
            h += s2 * sWc[(k + 2) * 64 + j];
            h += s3 * sWc[(k + 3) * 64 + j];
        }
        // h += x[node] @ W2a_top (x values wave-uniform)
        const float* xrow = x + (size_t)node * 32;
        #pragma unroll
        for (int k = 0; k < 32; ++k) h += xrow[k] * sW2ax[k * 64 + j];
        h = fmaxf(h, 0.f);

        // out = relu(h) @ W2b: halves split over k, combine with shfl_xor(32)
        int jo = lane & 31;
        int half = lane >> 5;
        float o = 0.f;
        #pragma unroll
        for (int kk = 0; kk < 32; ++kk) {
            float hk = __shfl(h, half * 32 + kk);
            o += hk * sW2b[(half * 32 + kk) * 32 + jo];
        }
        o += __shfl_xor(o, 32);
        if (lane < 32) out[(size_t)node * 32 + jo] = o + sb2b_[jo];
    }
}

// ---------------- fallback: per-edge atomic scatter + thread-per-node MLP ----------------
__global__ __launch_bounds__(256) void k_edge_atom(
    const float* __restrict__ x, const int* __restrict__ ei, const float* __restrict__ ea,
    const float* __restrict__ W1a, const float* __restrict__ b1a,
    float* __restrict__ Sacc, int E)
{
    __shared__ float sWB[32 * 64];
    __shared__ float sWA[32 * 64];
    __shared__ float sb[64];
    for (int t = threadIdx.x; t < 32 * 64; t += 256) {
        sWB[t] = W1a[32 * 64 + t];
        sWA[t] = W1a[t];
    }
    if (threadIdx.x < 64) sb[threadIdx.x] = b1a[threadIdx.x];
    __syncthreads();
    int e = blockIdx.x * 256 + threadIdx.x;
    if (e >= E) return;
    int row = ei[e];
    int col = ei[NE + e];
    float h[64];
    #pragma unroll
    for (int j = 0; j < 64; ++j) h[j] = sb[j];
    const float4* xrow = (const float4*)(x + (size_t)col * 32);
    #pragma unroll
    for (int k4 = 0; k4 < 8; ++k4) {
        float4 v = xrow[k4];
        float vv[4] = {v.x, v.y, v.z, v.w};
        #pragma unroll
        for (int c = 0; c < 4; ++c) {
            float val = vv[c];
            const float4* wr = (const float4*)&sWA[(k4 * 4 + c) * 64];
            #pragma unroll
            for (int j4 = 0; j4 < 16; ++j4) {
                float4 w = wr[j4];
                h[j4 * 4 + 0] += val * w.x; h[j4 * 4 + 1] += val * w.y;
                h[j4 * 4 + 2] += val * w.z; h[j4 * 4 + 3] += val * w.w;
            }
        }
    }
    const float4* earow = (const float4*)(ea + (size_t)e * 32);
    #pragma unroll
    for (int k4 = 0; k4 < 8; ++k4) {
        float4 v = earow[k4];
        float vv[4] = {v.x, v.y, v.z, v.w};
        #pragma unroll
        for (int c = 0; c < 4; ++c) {
            float val = vv[c];
            const float4* wr = (const float4*)&sWB[(k4 * 4 + c) * 64];
            #pragma unroll
            for (int j4 = 0; j4 < 16; ++j4) {
                float4 w = wr[j4];
                h[j4 * 4 + 0] += val * w.x; h[j4 * 4 + 1] += val * w.y;
                h[j4 * 4 + 2] += val * w.z; h[j4 * 4 + 3] += val * w.w;
            }
        }
    }
    float* srow = Sacc + (size_t)row * 64;
    #pragma unroll
    for (int j = 0; j < 64; ++j) atomicAdd(&srow[j], fmaxf(h[j], 0.f));
}

__global__ __launch_bounds__(256) void k_node(
    const float* __restrict__ x, const float* __restrict__ Sacc, const int* __restrict__ deg,
    const float* __restrict__ Wc, const float* __restrict__ bc,
    const float* __restrict__ W2a, const float* __restrict__ b2a,
    const float* __restrict__ W2b, const float* __restrict__ b2b,
    float* __restrict__ out, int N)
{
    __shared__ float sWc[64 * 64];
    __shared__ float sW2ax[32 * 64];
    __shared__ float sW2b[64 * 32];
    __shared__ float sbc2[64];
    __shared__ float sb2[64];
    __shared__ float sb2b_[32];
    for (int t = threadIdx.x; t < 64 * 64; t += 256) sWc[t] = Wc[t];
    for (int t = threadIdx.x; t < 32 * 64; t += 256) sW2ax[t] = W2a[t];
    for (int t = threadIdx.x; t < 64 * 32; t += 256) sW2b[t] = W2b[t];
    if (threadIdx.x < 64) {
        sbc2[threadIdx.x] = bc[threadIdx.x] + b2a[threadIdx.x];
        sb2[threadIdx.x] = b2a[threadIdx.x];
    }
    if (threadIdx.x < 32) sb2b_[threadIdx.x] = b2b[threadIdx.x];
    __syncthreads();

    int i = blockIdx.x * 256 + threadIdx.x;
    if (i >= N) return;
    int d = deg[i];
    float inv = (d > 0) ? 1.f / (float)d : 0.f;

    float h2[64];
    #pragma unroll
    for (int j = 0; j < 64; ++j) h2[j] = (d > 0) ? sbc2[j] : sb2[j];

    const float4* sp = (const float4*)(Sacc + (size_t)i * 64);
    #pragma unroll 2
    for (int k4 = 0; k4 < 16; ++k4) {
        float4 v = sp[k4];
        float vv[4] = {v.x * inv, v.y * inv, v.z * inv, v.w * inv};
        #pragma unroll
        for (int c = 0; c < 4; ++c) {
            float val = vv[c];
            const float4* wr = (const float4*)&sWc[(k4 * 4 + c) * 64];
            #pragma unroll
            for (int j4 = 0; j4 < 16; ++j4) {
                float4 w = wr[j4];
                h2[j4 * 4 + 0] += val * w.x; h2[j4 * 4 + 1] += val * w.y;
                h2[j4 * 4 + 2] += val * w.z; h2[j4 * 4 + 3] += val * w.w;
            }
        }
    }
    const float4* xrow = (const float4*)(x + (size_t)i * 32);
    #pragma unroll 2
    for (int k4 = 0; k4 < 8; ++k4) {
        float4 v = xrow[k4];
        float vv[4] = {v.x, v.y, v.z, v.w};
        #pragma unroll
        for (int c = 0; c < 4; ++c) {
            float val = vv[c];
            const float4* wr = (const float4*)&sW2ax[(k4 * 4 + c) * 64];
            #pragma unroll
            for (int j4 = 0; j4 < 16; ++j4) {
                float4 w = wr[j4];
                h2[j4 * 4 + 0] += val * w.x; h2[j4 * 4 + 1] += val * w.y;
                h2[j4 * 4 + 2] += val * w.z; h2[j4 * 4 + 3] += val * w.w;
            }
        }
    }
    #pragma unroll
    for (int j = 0; j < 64; ++j) h2[j] = fmaxf(h2[j], 0.f);

    float o[32];
    #pragma unroll
    for (int j = 0; j < 32; ++j) o[j] = sb2b_[j];
    #pragma unroll
    for (int k = 0; k < 64; ++k) {
        float val = h2[k];
        const float4* wr = (const float4*)&sW2b[k * 32];
        #pragma unroll
        for (int j4 = 0; j4 < 8; ++j4) {
            float4 w = wr[j4];
            o[j4 * 4 + 0] += val * w.x; o[j4 * 4 + 1] += val * w.y;
            o[j4 * 4 + 2] += val * w.z; o[j4 * 4 + 3] += val * w.w;
        }
    }
    float4* orow = (float4*)(out + (size_t)i * 32);
    #pragma unroll
    for (int q = 0; q < 8; ++q)
        orow[q] = make_float4(o[q * 4], o[q * 4 + 1], o[q * 4 + 2], o[q * 4 + 3]);
}

extern "C" void kernel_launch(void* const* d_in, const int* in_sizes, int n_in,
                              void* d_out, int out_size, void* d_ws, size_t ws_size,
                              hipStream_t stream) {
    const float* x   = (const float*)d_in[0];
    const int*   ei  = (const int*)d_in[1];
    const float* ea  = (const float*)d_in[2];
    const float* W1a = (const float*)d_in[5];
    const float* b1a = (const float*)d_in[6];
    const float* W1b = (const float*)d_in[7];
    const float* b1b = (const float*)d_in[8];
    const float* W2a = (const float*)d_in[9];
    const float* b2a = (const float*)d_in[10];
    const float* W2b = (const float*)d_in[11];
    const float* b2b = (const float*)d_in[12];
    float* out = (float*)d_out;

    // workspace layout (~219 MB)
    char* p = (char*)d_ws;
    int* deg        = (int*)p;        p += (size_t)NN * 4;
    int* offs       = (int*)p;        p += (size_t)NN * 4;
    int* bsums      = (int*)p;        p += 2048;
    float* Wc       = (float*)p;      p += 4096 * 4;
    float* bc       = (float*)p;      p += 64 * 4;
    uint4* wpack    = (uint4*)p;      p += 512 * 16;
    int* rank       = (int*)p;        p += (size_t)NE * 4;
    uint32* xbw     = (uint32*)p;     p += (size_t)NN * 16 * 4;   // [NN][32] bf16
    float* Sacc     = (float*)p;      p += (size_t)NN * 64 * 4;   // fallback only
    size_t off_g    = (size_t)(p - (char*)d_ws);
    uint32* g       = (uint32*)p;     // [NE][64] bf16 = 128B rows
    size_t need     = off_g + (size_t)NE * 128;

    dim3 blk(256);

    if (ws_size >= need) {
        hipMemsetAsync(deg, 0, (size_t)NN * 4, stream);
        hipLaunchKernelGGL(k_hist_prep, dim3(HB + PB), blk, 0, stream,
                           ei, deg, rank, W1b, b1b, W2a, W1a, x, Wc, bc, wpack, xbw, 1);
        hipLaunchKernelGGL(k_scan1, dim3(NB), blk, 0, stream, deg, offs, bsums, NN);
        hipLaunchKernelGGL(k_scan2, dim3(1), dim3(512), 0, stream, bsums, NB);
        hipLaunchKernelGGL(k_edge_mfma, dim3(NE / (64 * TPW)), blk, 0, stream,
                           ei, ea, xbw, wpack, b1a, rank, offs, bsums, g);
        hipLaunchKernelGGL(k_segnode, dim3(SN_BLOCKS), blk, 0, stream,
                           deg, offs, bsums, g, x, Wc, bc, W2a, b2a, W2b, b2b, out);
    } else {
        // fallback: fp32 atomic scatter (natural channel order)
        hipMemsetAsync(deg, 0, (size_t)NN * 4, stream);
        hipMemsetAsync(Sacc, 0, (size_t)NN * 64 * 4, stream);
        hipLaunchKernelGGL(k_hist_prep, dim3(HB + PB), blk, 0, stream,
                           ei, deg, rank, W1b, b1b, W2a, W1a, x, Wc, bc, wpack, xbw, 0);
        hipLaunchKernelGGL(k_edge_atom, dim3((NE + 255) / 256), blk, 0, stream,
                           x, ei, ea, W1a, b1a, Sacc, NE);
        hipLaunchKernelGGL(k_node, dim3(NB), blk, 0, stream,
                           x, Sacc, deg, Wc, bc, W2a, b2a, W2b, b2b, out, NN);
    }
}

// Round 14
// 310.524 us; speedup vs baseline: 1.3185x; 1.3185x over previous
//
#include <hip/hip_runtime.h>

#define NN 100000
#define NE 1600000
#define NB ((NN + 255) / 256)
#define TPW 8                      // 16-edge tiles per wave in k_edge_mfma
#define HB ((NE + 255) / 256)      // hist blocks = 6250
#define PB ((4096 + NN * 16 + 255) / 256)  // prep blocks

typedef unsigned int uint32;
typedef float f32x4 __attribute__((ext_vector_type(4)));
typedef short bf16x8 __attribute__((ext_vector_type(8)));

__device__ __forceinline__ float bflo(uint32 u) { return __uint_as_float(u << 16); }
__device__ __forceinline__ float bfhi(uint32 u) { return __uint_as_float(u & 0xffff0000u); }
__device__ __forceinline__ uint32 bfbits(float v) { return (__float_as_uint(v) + 0x8000u) >> 16; }
__device__ __forceinline__ uint32 pack2(float a, float b) { return bfbits(a) | (bfbits(b) << 16); }

// channel permutation: sigma(c) swaps cc (bits 5:4) and qq (bits 3:2) fields
__device__ __forceinline__ int sigma_ch(int c) {
    return (((c >> 2) & 3) << 4) + (((c >> 4) & 3) << 2) + (c & 3);
}

// ---------------- fused: histogram+rank  ||  Wc/bc/wpack/xbw prep ----------------
__global__ __launch_bounds__(256) void k_hist_prep(
    const int* __restrict__ ei, int* __restrict__ deg, int* __restrict__ rank,
    const float* __restrict__ W1b, const float* __restrict__ b1b,
    const float* __restrict__ W2a, const float* __restrict__ W1a, const float* __restrict__ x,
    float* __restrict__ Wc, float* __restrict__ bc,
    uint4* __restrict__ wpack, uint32* __restrict__ xbw, int perm)
{
    int b = blockIdx.x;
    if (b < HB) {
        int e = b * 256 + threadIdx.x;
        if (e < NE) rank[e] = atomicAdd(&deg[ei[e]], 1);
        return;
    }
    int idx = (b - HB) * 256 + threadIdx.x;
    if (idx < 4096) {
        int r = idx >> 6, c = idx & 63;
        float a = 0.f;
        for (int k = 0; k < 64; ++k) a += W1b[r * 64 + k] * W2a[(32 + k) * 64 + c];
        int rs = perm ? sigma_ch(r) : r;
        Wc[rs * 64 + c] = a;
        if (idx < 64) {
            float bacc = 0.f;
            for (int k = 0; k < 64; ++k) bacc += b1b[k] * W2a[(32 + k) * 64 + idx];
            bc[idx] = bacc;
        }
        if (idx < 512) {
            int table = idx >> 8;
            int cc = (idx >> 6) & 3;
            int lane = idx & 63;
            int qq = lane >> 4, en = lane & 15;
            int ch = cc * 16 + en;
            uint32 w[4];
            #pragma unroll
            for (int j = 0; j < 4; ++j) {
                int row0 = (table ? 0 : 32) + qq * 8 + j * 2;
                w[j] = pack2(W1a[row0 * 64 + ch], W1a[(row0 + 1) * 64 + ch]);
            }
            wpack[idx] = make_uint4(w[0], w[1], w[2], w[3]);
        }
    }
    int xi = idx - 4096;
    if (xi >= 0 && xi < NN * 16) {
        float2 v = *(const float2*)(x + (size_t)2 * xi);
        xbw[xi] = pack2(v.x, v.y);
    }
}

__global__ __launch_bounds__(256) void k_scan1(const int* __restrict__ deg, int* __restrict__ offs,
                                               int* __restrict__ bsums, int n) {
    __shared__ int s[256];
    int tid = threadIdx.x;
    int i = blockIdx.x * 256 + tid;
    int v = (i < n) ? deg[i] : 0;
    int acc = v;
    s[tid] = acc;
    __syncthreads();
    #pragma unroll
    for (int off = 1; off < 256; off <<= 1) {
        int t = (tid >= off) ? s[tid - off] : 0;
        __syncthreads();
        acc += t;
        s[tid] = acc;
        __syncthreads();
    }
    if (i < n) offs[i] = acc - v;
    if (tid == 255) bsums[blockIdx.x] = acc;
}

__global__ __launch_bounds__(512) void k_scan2(int* __restrict__ bsums, int nb) {
    __shared__ int s[512];
    int tid = threadIdx.x;
    int v = (tid < nb) ? bsums[tid] : 0;
    int acc = v;
    s[tid] = acc;
    __syncthreads();
    #pragma unroll
    for (int off = 1; off < 512; off <<= 1) {
        int t = (tid >= off) ? s[tid - off] : 0;
        __syncthreads();
        acc += t;
        s[tid] = acc;
        __syncthreads();
    }
    bsums[tid] = acc - v;
}

// ---------------- MFMA edge kernel: g[slot(e)] = bf16(relu(b1a + x[col]@W1a_top + ea@W1a_bot)) ----------------
// slot computed inline: rank[e] + offs[row] + bsums[row>>8]
// A = wpack fragments (channels on M), B = ea row / xb row (edge on col), C init = b1a.
// D/C: lane(qq,en) -> col(edge)=en, channel cc*16+qq*4+r; write = sigma word order (matches Wc).
__global__ __launch_bounds__(256) void k_edge_mfma(
    const int* __restrict__ ei, const float* __restrict__ ea, const uint32* __restrict__ xbw,
    const uint4* __restrict__ wpack, const float* __restrict__ b1a,
    const int* __restrict__ rank, const int* __restrict__ offs, const int* __restrict__ bsums,
    uint32* __restrict__ g)
{
    int lane = threadIdx.x & 63;
    int wave = threadIdx.x >> 6;
    int en = lane & 15;
    int qq = lane >> 4;

    union U { uint4 u; bf16x8 v; };
    U wB[4], wA[4];
    #pragma unroll
    for (int cc = 0; cc < 4; ++cc) {
        wB[cc].u = wpack[cc * 64 + lane];
        wA[cc].u = wpack[256 + cc * 64 + lane];
    }
    f32x4 binit[4];
    #pragma unroll
    for (int cc = 0; cc < 4; ++cc) {
        float4 b = *(const float4*)(b1a + cc * 16 + qq * 4);
        binit[cc] = (f32x4){b.x, b.y, b.z, b.w};
    }

    int base = blockIdx.x * (64 * TPW) + wave * (16 * TPW);

    // ---- prologue: tile 0 fully resolved, tile 1 level-1 issued ----
    int e0 = base + en;
    int r0 = ei[e0];
    int c0 = ei[NE + e0];
    int k0 = rank[e0];
    float4 f0a = *(const float4*)(ea + (size_t)e0 * 32 + qq * 8);
    float4 f0b = *(const float4*)(ea + (size_t)e0 * 32 + qq * 8 + 4);
    int p0 = k0 + offs[r0] + bsums[r0 >> 8];

    int e1 = base + 16 + en;
    int r1 = ei[e1];
    int c1 = ei[NE + e1];
    int k1 = rank[e1];
    float4 f1a = *(const float4*)(ea + (size_t)e1 * 32 + qq * 8);
    float4 f1b = *(const float4*)(ea + (size_t)e1 * 32 + qq * 8 + 4);

    uint4 xv0 = *(const uint4*)(xbw + (size_t)c0 * 16 + qq * 4);

    #pragma unroll 1
    for (int t = 0; t < TPW; ++t) {
        // prefetch tile t+2 (clamped; clamped values never used in compute)
        int e2 = base + (t + 2) * 16 + en;
        if (e2 > NE - 1) e2 = NE - 1;
        int r2 = ei[e2];
        int c2 = ei[NE + e2];
        int k2 = rank[e2];
        float4 f2a = *(const float4*)(ea + (size_t)e2 * 32 + qq * 8);
        float4 f2b = *(const float4*)(ea + (size_t)e2 * 32 + qq * 8 + 4);
        // resolve tile t+1: slot + xb gather
        int p1 = k1 + offs[r1] + bsums[r1 >> 8];
        uint4 xv1 = *(const uint4*)(xbw + (size_t)c1 * 16 + qq * 4);

        // ---- compute tile t ----
        U bea, bx;
        bea.u.x = pack2(f0a.x, f0a.y);
        bea.u.y = pack2(f0a.z, f0a.w);
        bea.u.z = pack2(f0b.x, f0b.y);
        bea.u.w = pack2(f0b.z, f0b.w);
        bx.u = xv0;

        f32x4 acc[4];
        #pragma unroll
        for (int cc = 0; cc < 4; ++cc) acc[cc] = binit[cc];
        #pragma unroll
        for (int cc = 0; cc < 4; ++cc)
            acc[cc] = __builtin_amdgcn_mfma_f32_16x16x32_bf16(wB[cc].v, bea.v, acc[cc], 0, 0, 0);
        #pragma unroll
        for (int cc = 0; cc < 4; ++cc)
            acc[cc] = __builtin_amdgcn_mfma_f32_16x16x32_bf16(wA[cc].v, bx.v, acc[cc], 0, 0, 0);

        uint4 o0, o1;
        o0.x = pack2(fmaxf(acc[0][0], 0.f), fmaxf(acc[0][1], 0.f));
        o0.y = pack2(fmaxf(acc[0][2], 0.f), fmaxf(acc[0][3], 0.f));
        o0.z = pack2(fmaxf(acc[1][0], 0.f), fmaxf(acc[1][1], 0.f));
        o0.w = pack2(fmaxf(acc[1][2], 0.f), fmaxf(acc[1][3], 0.f));
        o1.x = pack2(fmaxf(acc[2][0], 0.f), fmaxf(acc[2][1], 0.f));
        o1.y = pack2(fmaxf(acc[2][2], 0.f), fmaxf(acc[2][3], 0.f));
        o1.z = pack2(fmaxf(acc[3][0], 0.f), fmaxf(acc[3][1], 0.f));
        o1.w = pack2(fmaxf(acc[3][2], 0.f), fmaxf(acc[3][3], 0.f));
        uint4* gp = (uint4*)(g + (size_t)p0 * 32 + qq * 8);
        gp[0] = o0;
        gp[1] = o1;

        // ---- rotate (all names static) ----
        p0 = p1; f0a = f1a; f0b = f1b; xv0 = xv1;
        r1 = r2; c1 = c2; k1 = k2; f1a = f2a; f1b = f2b;
    }
}

// ---------------- segment sum over contiguous g rows: wave/node, 4 rows/iter ----------------
__global__ __launch_bounds__(256) void k_seg_c(
    const int* __restrict__ deg, const int* __restrict__ offs, const int* __restrict__ bsums,
    const uint32* __restrict__ g, float* __restrict__ Sacc)
{
    int node = blockIdx.x * 4 + (threadIdx.x >> 6);
    if (node >= NN) return;
    int lane = threadIdx.x & 63;
    int quarter = lane >> 4;
    int wi = lane & 15;
    int d = deg[node];
    size_t start = (size_t)(offs[node] + bsums[node >> 8]);

    float4 S = {0.f, 0.f, 0.f, 0.f};
    int r = quarter;
    for (; r + 4 < d; r += 8) {
        uint2 u1 = *(const uint2*)(g + (start + r) * 32 + wi * 2);
        uint2 u2 = *(const uint2*)(g + (start + r + 4) * 32 + wi * 2);
        S.x += bflo(u1.x) + bflo(u2.x);
        S.y += bfhi(u1.x) + bfhi(u2.x);
        S.z += bflo(u1.y) + bflo(u2.y);
        S.w += bfhi(u1.y) + bfhi(u2.y);
    }
    if (r < d) {
        uint2 u = *(const uint2*)(g + (start + r) * 32 + wi * 2);
        S.x += bflo(u.x); S.y += bfhi(u.x); S.z += bflo(u.y); S.w += bfhi(u.y);
    }
    S.x += __shfl_xor(S.x, 16); S.y += __shfl_xor(S.y, 16);
    S.z += __shfl_xor(S.z, 16); S.w += __shfl_xor(S.w, 16);
    S.x += __shfl_xor(S.x, 32); S.y += __shfl_xor(S.y, 32);
    S.z += __shfl_xor(S.z, 32); S.w += __shfl_xor(S.w, 32);
    if (quarter == 0)
        *(float4*)(Sacc + (size_t)node * 64 + wi * 4) = make_float4(S.x, S.y, S.z, S.w);
}

// ---------------- node MLP: out = relu(x@W2a_top + (Sacc/d)@Wc + bc + b2a) @ W2b + b2b ----------------
__global__ __launch_bounds__(256) void k_node(
    const float* __restrict__ x, const float* __restrict__ Sacc, const int* __restrict__ deg,
    const float* __restrict__ Wc, const float* __restrict__ bc,
    const float* __restrict__ W2a, const float* __restrict__ b2a,
    const float* __restrict__ W2b, const float* __restrict__ b2b,
    float* __restrict__ out, int N)
{
    __shared__ float sWc[64 * 64];
    __shared__ float sW2ax[32 * 64];
    __shared__ float sW2b[64 * 32];
    __shared__ float sbc2[64];
    __shared__ float sb2[64];
    __shared__ float sb2b_[32];
    for (int t = threadIdx.x; t < 64 * 64; t += 256) sWc[t] = Wc[t];
    for (int t = threadIdx.x; t < 32 * 64; t += 256) sW2ax[t] = W2a[t];
    for (int t = threadIdx.x; t < 64 * 32; t += 256) sW2b[t] = W2b[t];
    if (threadIdx.x < 64) {
        sbc2[threadIdx.x] = bc[threadIdx.x] + b2a[threadIdx.x];
        sb2[threadIdx.x] = b2a[threadIdx.x];
    }
    if (threadIdx.x < 32) sb2b_[threadIdx.x] = b2b[threadIdx.x];
    __syncthreads();

    int i = blockIdx.x * 256 + threadIdx.x;
    if (i >= N) return;
    int d = deg[i];
    float inv = (d > 0) ? 1.f / (float)d : 0.f;

    float h2[64];
    #pragma unroll
    for (int j = 0; j < 64; ++j) h2[j] = (d > 0) ? sbc2[j] : sb2[j];

    const float4* sp = (const float4*)(Sacc + (size_t)i * 64);
    #pragma unroll 2
    for (int k4 = 0; k4 < 16; ++k4) {
        float4 v = sp[k4];
        float vv[4] = {v.x * inv, v.y * inv, v.z * inv, v.w * inv};
        #pragma unroll
        for (int c = 0; c < 4; ++c) {
            float val = vv[c];
            const float4* wr = (const float4*)&sWc[(k4 * 4 + c) * 64];
            #pragma unroll
            for (int j4 = 0; j4 < 16; ++j4) {
                float4 w = wr[j4];
                h2[j4 * 4 + 0] += val * w.x; h2[j4 * 4 + 1] += val * w.y;
                h2[j4 * 4 + 2] += val * w.z; h2[j4 * 4 + 3] += val * w.w;
            }
        }
    }
    const float4* xrow = (const float4*)(x + (size_t)i * 32);
    #pragma unroll 2
    for (int k4 = 0; k4 < 8; ++k4) {
        float4 v = xrow[k4];
        float vv[4] = {v.x, v.y, v.z, v.w};
        #pragma unroll
        for (int c = 0; c < 4; ++c) {
            float val = vv[c];
            const float4* wr = (const float4*)&sW2ax[(k4 * 4 + c) * 64];
            #pragma unroll
            for (int j4 = 0; j4 < 16; ++j4) {
                float4 w = wr[j4];
                h2[j4 * 4 + 0] += val * w.x; h2[j4 * 4 + 1] += val * w.y;
                h2[j4 * 4 + 2] += val * w.z; h2[j4 * 4 + 3] += val * w.w;
            }
        }
    }
    #pragma unroll
    for (int j = 0; j < 64; ++j) h2[j] = fmaxf(h2[j], 0.f);

    float o[32];
    #pragma unroll
    for (int j = 0; j < 32; ++j) o[j] = sb2b_[j];
    #pragma unroll
    for (int k = 0; k < 64; ++k) {
        float val = h2[k];
        const float4* wr = (const float4*)&sW2b[k * 32];
        #pragma unroll
        for (int j4 = 0; j4 < 8; ++j4) {
            float4 w = wr[j4];
            o[j4 * 4 + 0] += val * w.x; o[j4 * 4 + 1] += val * w.y;
            o[j4 * 4 + 2] += val * w.z; o[j4 * 4 + 3] += val * w.w;
        }
    }
    float4* orow = (float4*)(out + (size_t)i * 32);
    #pragma unroll
    for (int q = 0; q < 8; ++q)
        orow[q] = make_float4(o[q * 4], o[q * 4 + 1], o[q * 4 + 2], o[q * 4 + 3]);
}

// ---------------- fallback: per-edge atomic scatter (natural channel order) ----------------
__global__ __launch_bounds__(256) void k_edge_atom(
    const float* __restrict__ x, const int* __restrict__ ei, const float* __restrict__ ea,
    const float* __restrict__ W1a, const float* __restrict__ b1a,
    float* __restrict__ Sacc, int E)
{
    __shared__ float sWB[32 * 64];
    __shared__ float sWA[32 * 64];
    __shared__ float sb[64];
    for (int t = threadIdx.x; t < 32 * 64; t += 256) {
        sWB[t] = W1a[32 * 64 + t];
        sWA[t] = W1a[t];
    }
    if (threadIdx.x < 64) sb[threadIdx.x] = b1a[threadIdx.x];
    __syncthreads();
    int e = blockIdx.x * 256 + threadIdx.x;
    if (e >= E) return;
    int row = ei[e];
    int col = ei[NE + e];
    float h[64];
    #pragma unroll
    for (int j = 0; j < 64; ++j) h[j] = sb[j];
    const float4* xrow = (const float4*)(x + (size_t)col * 32);
    #pragma unroll
    for (int k4 = 0; k4 < 8; ++k4) {
        float4 v = xrow[k4];
        float vv[4] = {v.x, v.y, v.z, v.w};
        #pragma unroll
        for (int c = 0; c < 4; ++c) {
            float val = vv[c];
            const float4* wr = (const float4*)&sWA[(k4 * 4 + c) * 64];
            #pragma unroll
            for (int j4 = 0; j4 < 16; ++j4) {
                float4 w = wr[j4];
                h[j4 * 4 + 0] += val * w.x; h[j4 * 4 + 1] += val * w.y;
                h[j4 * 4 + 2] += val * w.z; h[j4 * 4 + 3] += val * w.w;
            }
        }
    }
    const float4* earow = (const float4*)(ea + (size_t)e * 32);
    #pragma unroll
    for (int k4 = 0; k4 < 8; ++k4) {
        float4 v = earow[k4];
        float vv[4] = {v.x, v.y, v.z, v.w};
        #pragma unroll
        for (int c = 0; c < 4; ++c) {
            float val = vv[c];
            const float4* wr = (const float4*)&sWB[(k4 * 4 + c) * 64];
            #pragma unroll
            for (int j4 = 0; j4 < 16; ++j4) {
                float4 w = wr[j4];
                h[j4 * 4 + 0] += val * w.x; h[j4 * 4 + 1] += val * w.y;
                h[j4 * 4 + 2] += val * w.z; h[j4 * 4 + 3] += val * w.w;
            }
        }
    }
    float* srow = Sacc + (size_t)row * 64;
    #pragma unroll
    for (int j = 0; j < 64; ++j) atomicAdd(&srow[j], fmaxf(h[j], 0.f));
}

extern "C" void kernel_launch(void* const* d_in, const int* in_sizes, int n_in,
                              void* d_out, int out_size, void* d_ws, size_t ws_size,
                              hipStream_t stream) {
    const float* x   = (const float*)d_in[0];
    const int*   ei  = (const int*)d_in[1];
    const float* ea  = (const float*)d_in[2];
    const float* W1a = (const float*)d_in[5];
    const float* b1a = (const float*)d_in[6];
    const float* W1b = (const float*)d_in[7];
    const float* b1b = (const float*)d_in[8];
    const float* W2a = (const float*)d_in[9];
    const float* b2a = (const float*)d_in[10];
    const float* W2b = (const float*)d_in[11];
    const float* b2b = (const float*)d_in[12];
    float* out = (float*)d_out;

    // workspace layout (~244 MB)
    char* p = (char*)d_ws;
    int* deg        = (int*)p;        p += (size_t)NN * 4;
    int* offs       = (int*)p;        p += (size_t)NN * 4;
    int* bsums      = (int*)p;        p += 2048;
    float* Wc       = (float*)p;      p += 4096 * 4;
    float* bc       = (float*)p;      p += 64 * 4;
    uint4* wpack    = (uint4*)p;      p += 512 * 16;
    int* rank       = (int*)p;        p += (size_t)NE * 4;
    uint32* xbw     = (uint32*)p;     p += (size_t)NN * 16 * 4;   // [NN][32] bf16
    float* Sacc     = (float*)p;      p += (size_t)NN * 64 * 4;
    size_t off_g    = (size_t)(p - (char*)d_ws);
    uint32* g       = (uint32*)p;     // [NE][64] bf16 = 128B rows
    size_t need     = off_g + (size_t)NE * 128;

    dim3 blk(256);

    if (ws_size >= need) {
        hipMemsetAsync(deg, 0, (size_t)NN * 4, stream);
        hipLaunchKernelGGL(k_hist_prep, dim3(HB + PB), blk, 0, stream,
                           ei, deg, rank, W1b, b1b, W2a, W1a, x, Wc, bc, wpack, xbw, 1);
        hipLaunchKernelGGL(k_scan1, dim3(NB), blk, 0, stream, deg, offs, bsums, NN);
        hipLaunchKernelGGL(k_scan2, dim3(1), dim3(512), 0, stream, bsums, NB);
        hipLaunchKernelGGL(k_edge_mfma, dim3(NE / (64 * TPW)), blk, 0, stream,
                           ei, ea, xbw, wpack, b1a, rank, offs, bsums, g);
        hipLaunchKernelGGL(k_seg_c, dim3((NN + 3) / 4), blk, 0, stream, deg, offs, bsums, g, Sacc);
        hipLaunchKernelGGL(k_node, dim3(NB), blk, 0, stream,
                           x, Sacc, deg, Wc, bc, W2a, b2a, W2b, b2b, out, NN);
    } else {
        // fallback: fp32 atomic scatter (natural channel order)
        hipMemsetAsync(deg, 0, (size_t)NN * 4, stream);
        hipMemsetAsync(Sacc, 0, (size_t)NN * 64 * 4, stream);
        hipLaunchKernelGGL(k_hist_prep, dim3(HB + PB), blk, 0, stream,
                           ei, deg, rank, W1b, b1b, W2a, W1a, x, Wc, bc, wpack, xbw, 0);
        hipLaunchKernelGGL(k_edge_atom, dim3((NE + 255) / 256), blk, 0, stream,
                           x, ei, ea, W1a, b1a, Sacc, NE);
        hipLaunchKernelGGL(k_node, dim3(NB), blk, 0, stream,
                           x, Sacc, deg, Wc, bc, W2a, b2a, W2b, b2b, out, NN);
    }
}

// Round 15
// 298.647 us; speedup vs baseline: 1.3709x; 1.0398x over previous
//
#include <hip/hip_runtime.h>

#define NN 100000
#define NE 1600000
#define NB ((NN + 255) / 256)
#define TPW 8                      // 16-edge tiles per wave in k_edge_mfma
#define HB ((NE + 255) / 256)      // hist blocks = 6250
#define PB ((4096 + NN * 16 + 255) / 256)  // prep blocks

typedef unsigned int uint32;
typedef float f32x4 __attribute__((ext_vector_type(4)));
typedef short bf16x8 __attribute__((ext_vector_type(8)));

__device__ __forceinline__ float bflo(uint32 u) { return __uint_as_float(u << 16); }
__device__ __forceinline__ float bfhi(uint32 u) { return __uint_as_float(u & 0xffff0000u); }
__device__ __forceinline__ uint32 bfbits(float v) { return (__float_as_uint(v) + 0x8000u) >> 16; }
__device__ __forceinline__ uint32 pack2(float a, float b) { return bfbits(a) | (bfbits(b) << 16); }

// channel permutation: sigma(c) swaps cc (bits 5:4) and qq (bits 3:2) fields
__device__ __forceinline__ int sigma_ch(int c) {
    return (((c >> 2) & 3) << 4) + (((c >> 4) & 3) << 2) + (c & 3);
}

// ---------------- fused: histogram+rank  ||  Wc/bc/wpack/xbw prep ----------------
__global__ __launch_bounds__(256) void k_hist_prep(
    const int* __restrict__ ei, int* __restrict__ deg, int* __restrict__ rank,
    const float* __restrict__ W1b, const float* __restrict__ b1b,
    const float* __restrict__ W2a, const float* __restrict__ W1a, const float* __restrict__ x,
    float* __restrict__ Wc, float* __restrict__ bc,
    uint4* __restrict__ wpack, uint32* __restrict__ xbw, int perm)
{
    int b = blockIdx.x;
    if (b < HB) {
        int e = b * 256 + threadIdx.x;
        if (e < NE) rank[e] = atomicAdd(&deg[ei[e]], 1);
        return;
    }
    int idx = (b - HB) * 256 + threadIdx.x;
    if (idx < 4096) {
        int r = idx >> 6, c = idx & 63;
        float a = 0.f;
        for (int k = 0; k < 64; ++k) a += W1b[r * 64 + k] * W2a[(32 + k) * 64 + c];
        int rs = perm ? sigma_ch(r) : r;
        Wc[rs * 64 + c] = a;
        if (idx < 64) {
            float bacc = 0.f;
            for (int k = 0; k < 64; ++k) bacc += b1b[k] * W2a[(32 + k) * 64 + idx];
            bc[idx] = bacc;
        }
        if (idx < 512) {
            int table = idx >> 8;
            int cc = (idx >> 6) & 3;
            int lane = idx & 63;
            int qq = lane >> 4, en = lane & 15;
            int ch = cc * 16 + en;
            uint32 w[4];
            #pragma unroll
            for (int j = 0; j < 4; ++j) {
                int row0 = (table ? 0 : 32) + qq * 8 + j * 2;
                w[j] = pack2(W1a[row0 * 64 + ch], W1a[(row0 + 1) * 64 + ch]);
            }
            wpack[idx] = make_uint4(w[0], w[1], w[2], w[3]);
        }
    }
    int xi = idx - 4096;
    if (xi >= 0 && xi < NN * 16) {
        float2 v = *(const float2*)(x + (size_t)2 * xi);
        xbw[xi] = pack2(v.x, v.y);
    }
}

__global__ __launch_bounds__(256) void k_scan1(const int* __restrict__ deg, int* __restrict__ offs,
                                               int* __restrict__ bsums, int n) {
    __shared__ int s[256];
    int tid = threadIdx.x;
    int i = blockIdx.x * 256 + tid;
    int v = (i < n) ? deg[i] : 0;
    int acc = v;
    s[tid] = acc;
    __syncthreads();
    #pragma unroll
    for (int off = 1; off < 256; off <<= 1) {
        int t = (tid >= off) ? s[tid - off] : 0;
        __syncthreads();
        acc += t;
        s[tid] = acc;
        __syncthreads();
    }
    if (i < n) offs[i] = acc - v;
    if (tid == 255) bsums[blockIdx.x] = acc;
}

__global__ __launch_bounds__(512) void k_scan2(int* __restrict__ bsums, int nb) {
    __shared__ int s[512];
    int tid = threadIdx.x;
    int v = (tid < nb) ? bsums[tid] : 0;
    int acc = v;
    s[tid] = acc;
    __syncthreads();
    #pragma unroll
    for (int off = 1; off < 512; off <<= 1) {
        int t = (tid >= off) ? s[tid - off] : 0;
        __syncthreads();
        acc += t;
        s[tid] = acc;
        __syncthreads();
    }
    bsums[tid] = acc - v;
}

// finalize pos in place: pos[e] = rank + offs[row] + bsums[row>>8]
__global__ __launch_bounds__(256) void k_pos(const int* __restrict__ ei, const int* __restrict__ offs,
                                             const int* __restrict__ bsums, int* __restrict__ pos, int E) {
    int e = blockIdx.x * 256 + threadIdx.x;
    if (e >= E) return;
    int r = ei[e];
    pos[e] += offs[r] + bsums[r >> 8];
}

// ---------------- MFMA edge kernel: g[pos[e]] = bf16(relu(b1a + x[col]@W1a_top + ea@W1a_bot)) ----------------
// A = wpack fragments (channels on M), B = ea row / xb row (edge on col), C init = b1a.
// D/C: lane(qq,en) -> col(edge)=en, channel cc*16+qq*4+r; write = sigma word order (matches Wc).
// Depth-2 software pipeline; sequential ea/pos reads, random 128B g write; no LDS.
__global__ __launch_bounds__(256) void k_edge_mfma(
    const int* __restrict__ ei, const float* __restrict__ ea, const uint32* __restrict__ xbw,
    const uint4* __restrict__ wpack, const float* __restrict__ b1a,
    const int* __restrict__ pos, uint32* __restrict__ g)
{
    int lane = threadIdx.x & 63;
    int wave = threadIdx.x >> 6;
    int en = lane & 15;
    int qq = lane >> 4;

    union U { uint4 u; bf16x8 v; };
    U wB[4], wA[4];
    #pragma unroll
    for (int cc = 0; cc < 4; ++cc) {
        wB[cc].u = wpack[cc * 64 + lane];
        wA[cc].u = wpack[256 + cc * 64 + lane];
    }
    f32x4 binit[4];
    #pragma unroll
    for (int cc = 0; cc < 4; ++cc) {
        float4 b = *(const float4*)(b1a + cc * 16 + qq * 4);
        binit[cc] = (f32x4){b.x, b.y, b.z, b.w};
    }

    int base = blockIdx.x * (64 * TPW) + wave * (16 * TPW);

    // ---- prologue: tile 0 full chain, tile 1 level-1 ----
    int e0 = base + en;
    int p0 = pos[e0];
    int c0 = ei[NE + e0];
    float4 f0a = *(const float4*)(ea + (size_t)e0 * 32 + qq * 8);
    float4 f0b = *(const float4*)(ea + (size_t)e0 * 32 + qq * 8 + 4);

    int e1 = base + 16 + en;
    int p1 = pos[e1];
    int c1 = ei[NE + e1];
    float4 f1a = *(const float4*)(ea + (size_t)e1 * 32 + qq * 8);
    float4 f1b = *(const float4*)(ea + (size_t)e1 * 32 + qq * 8 + 4);

    uint4 xv0 = *(const uint4*)(xbw + (size_t)c0 * 16 + qq * 4);

    #pragma unroll 1
    for (int t = 0; t < TPW; ++t) {
        // prefetch tile t+2 (clamped; clamped values never used in compute)
        int e2 = base + (t + 2) * 16 + en;
        if (e2 > NE - 1) e2 = NE - 1;
        int p2 = pos[e2];
        int c2 = ei[NE + e2];
        float4 f2a = *(const float4*)(ea + (size_t)e2 * 32 + qq * 8);
        float4 f2b = *(const float4*)(ea + (size_t)e2 * 32 + qq * 8 + 4);
        // xb gather for tile t+1
        uint4 xv1 = *(const uint4*)(xbw + (size_t)c1 * 16 + qq * 4);

        // ---- compute tile t ----
        U bea, bx;
        bea.u.x = pack2(f0a.x, f0a.y);
        bea.u.y = pack2(f0a.z, f0a.w);
        bea.u.z = pack2(f0b.x, f0b.y);
        bea.u.w = pack2(f0b.z, f0b.w);
        bx.u = xv0;

        f32x4 acc[4];
        #pragma unroll
        for (int cc = 0; cc < 4; ++cc) acc[cc] = binit[cc];
        #pragma unroll
        for (int cc = 0; cc < 4; ++cc)
            acc[cc] = __builtin_amdgcn_mfma_f32_16x16x32_bf16(wB[cc].v, bea.v, acc[cc], 0, 0, 0);
        #pragma unroll
        for (int cc = 0; cc < 4; ++cc)
            acc[cc] = __builtin_amdgcn_mfma_f32_16x16x32_bf16(wA[cc].v, bx.v, acc[cc], 0, 0, 0);

        uint4 o0, o1;
        o0.x = pack2(fmaxf(acc[0][0], 0.f), fmaxf(acc[0][1], 0.f));
        o0.y = pack2(fmaxf(acc[0][2], 0.f), fmaxf(acc[0][3], 0.f));
        o0.z = pack2(fmaxf(acc[1][0], 0.f), fmaxf(acc[1][1], 0.f));
        o0.w = pack2(fmaxf(acc[1][2], 0.f), fmaxf(acc[1][3], 0.f));
        o1.x = pack2(fmaxf(acc[2][0], 0.f), fmaxf(acc[2][1], 0.f));
        o1.y = pack2(fmaxf(acc[2][2], 0.f), fmaxf(acc[2][3], 0.f));
        o1.z = pack2(fmaxf(acc[3][0], 0.f), fmaxf(acc[3][1], 0.f));
        o1.w = pack2(fmaxf(acc[3][2], 0.f), fmaxf(acc[3][3], 0.f));
        uint4* gp = (uint4*)(g + (size_t)p0 * 32 + qq * 8);
        gp[0] = o0;
        gp[1] = o1;

        // ---- rotate (all names static) ----
        p0 = p1; f0a = f1a; f0b = f1b; xv0 = xv1;
        p1 = p2; c1 = c2; f1a = f2a; f1b = f2b;
    }
}

// ---------------- segment sum over contiguous g rows: wave/node, 4 rows/iter ----------------
__global__ __launch_bounds__(256) void k_seg_c(
    const int* __restrict__ deg, const int* __restrict__ offs, const int* __restrict__ bsums,
    const uint32* __restrict__ g, float* __restrict__ Sacc)
{
    int node = blockIdx.x * 4 + (threadIdx.x >> 6);
    if (node >= NN) return;
    int lane = threadIdx.x & 63;
    int quarter = lane >> 4;
    int wi = lane & 15;
    int d = deg[node];
    size_t start = (size_t)(offs[node] + bsums[node >> 8]);

    float4 S = {0.f, 0.f, 0.f, 0.f};
    int r = quarter;
    for (; r + 4 < d; r += 8) {
        uint2 u1 = *(const uint2*)(g + (start + r) * 32 + wi * 2);
        uint2 u2 = *(const uint2*)(g + (start + r + 4) * 32 + wi * 2);
        S.x += bflo(u1.x) + bflo(u2.x);
        S.y += bfhi(u1.x) + bfhi(u2.x);
        S.z += bflo(u1.y) + bflo(u2.y);
        S.w += bfhi(u1.y) + bfhi(u2.y);
    }
    if (r < d) {
        uint2 u = *(const uint2*)(g + (start + r) * 32 + wi * 2);
        S.x += bflo(u.x); S.y += bfhi(u.x); S.z += bflo(u.y); S.w += bfhi(u.y);
    }
    S.x += __shfl_xor(S.x, 16); S.y += __shfl_xor(S.y, 16);
    S.z += __shfl_xor(S.z, 16); S.w += __shfl_xor(S.w, 16);
    S.x += __shfl_xor(S.x, 32); S.y += __shfl_xor(S.y, 32);
    S.z += __shfl_xor(S.z, 32); S.w += __shfl_xor(S.w, 32);
    if (quarter == 0)
        *(float4*)(Sacc + (size_t)node * 64 + wi * 4) = make_float4(S.x, S.y, S.z, S.w);
}

// ---------------- node MLP: out = relu(x@W2a_top + (Sacc/d)@Wc + bc + b2a) @ W2b + b2b ----------------
__global__ __launch_bounds__(256) void k_node(
    const float* __restrict__ x, const float* __restrict__ Sacc, const int* __restrict__ deg,
    const float* __restrict__ Wc, const float* __restrict__ bc,
    const float* __restrict__ W2a, const float* __restrict__ b2a,
    const float* __restrict__ W2b, const float* __restrict__ b2b,
    float* __restrict__ out, int N)
{
    __shared__ float sWc[64 * 64];
    __shared__ float sW2ax[32 * 64];
    __shared__ float sW2b[64 * 32];
    __shared__ float sbc2[64];
    __shared__ float sb2[64];
    __shared__ float sb2b_[32];
    for (int t = threadIdx.x; t < 64 * 64; t += 256) sWc[t] = Wc[t];
    for (int t = threadIdx.x; t < 32 * 64; t += 256) sW2ax[t] = W2a[t];
    for (int t = threadIdx.x; t < 64 * 32; t += 256) sW2b[t] = W2b[t];
    if (threadIdx.x < 64) {
        sbc2[threadIdx.x] = bc[threadIdx.x] + b2a[threadIdx.x];
        sb2[threadIdx.x] = b2a[threadIdx.x];
    }
    if (threadIdx.x < 32) sb2b_[threadIdx.x] = b2b[threadIdx.x];
    __syncthreads();

    int i = blockIdx.x * 256 + threadIdx.x;
    if (i >= N) return;
    int d = deg[i];
    float inv = (d > 0) ? 1.f / (float)d : 0.f;

    float h2[64];
    #pragma unroll
    for (int j = 0; j < 64; ++j) h2[j] = (d > 0) ? sbc2[j] : sb2[j];

    const float4* sp = (const float4*)(Sacc + (size_t)i * 64);
    #pragma unroll 2
    for (int k4 = 0; k4 < 16; ++k4) {
        float4 v = sp[k4];
        float vv[4] = {v.x * inv, v.y * inv, v.z * inv, v.w * inv};
        #pragma unroll
        for (int c = 0; c < 4; ++c) {
            float val = vv[c];
            const float4* wr = (const float4*)&sWc[(k4 * 4 + c) * 64];
            #pragma unroll
            for (int j4 = 0; j4 < 16; ++j4) {
                float4 w = wr[j4];
                h2[j4 * 4 + 0] += val * w.x; h2[j4 * 4 + 1] += val * w.y;
                h2[j4 * 4 + 2] += val * w.z; h2[j4 * 4 + 3] += val * w.w;
            }
        }
    }
    const float4* xrow = (const float4*)(x + (size_t)i * 32);
    #pragma unroll 2
    for (int k4 = 0; k4 < 8; ++k4) {
        float4 v = xrow[k4];
        float vv[4] = {v.x, v.y, v.z, v.w};
        #pragma unroll
        for (int c = 0; c < 4; ++c) {
            float val = vv[c];
            const float4* wr = (const float4*)&sW2ax[(k4 * 4 + c) * 64];
            #pragma unroll
            for (int j4 = 0; j4 < 16; ++j4) {
                float4 w = wr[j4];
                h2[j4 * 4 + 0] += val * w.x; h2[j4 * 4 + 1] += val * w.y;
                h2[j4 * 4 + 2] += val * w.z; h2[j4 * 4 + 3] += val * w.w;
            }
        }
    }
    #pragma unroll
    for (int j = 0; j < 64; ++j) h2[j] = fmaxf(h2[j], 0.f);

    float o[32];
    #pragma unroll
    for (int j = 0; j < 32; ++j) o[j] = sb2b_[j];
    #pragma unroll
    for (int k = 0; k < 64; ++k) {
        float val = h2[k];
        const float4* wr = (const float4*)&sW2b[k * 32];
        #pragma unroll
        for (int j4 = 0; j4 < 8; ++j4) {
            float4 w = wr[j4];
            o[j4 * 4 + 0] += val * w.x; o[j4 * 4 + 1] += val * w.y;
            o[j4 * 4 + 2] += val * w.z; o[j4 * 4 + 3] += val * w.w;
        }
    }
    float4* orow = (float4*)(out + (size_t)i * 32);
    #pragma unroll
    for (int q = 0; q < 8; ++q)
        orow[q] = make_float4(o[q * 4], o[q * 4 + 1], o[q * 4 + 2], o[q * 4 + 3]);
}

// ---------------- fallback: per-edge atomic scatter (natural channel order) ----------------
__global__ __launch_bounds__(256) void k_edge_atom(
    const float* __restrict__ x, const int* __restrict__ ei, const float* __restrict__ ea,
    const float* __restrict__ W1a, const float* __restrict__ b1a,
    float* __restrict__ Sacc, int E)
{
    __shared__ float sWB[32 * 64];
    __shared__ float sWA[32 * 64];
    __shared__ float sb[64];
    for (int t = threadIdx.x; t < 32 * 64; t += 256) {
        sWB[t] = W1a[32 * 64 + t];
        sWA[t] = W1a[t];
    }
    if (threadIdx.x < 64) sb[threadIdx.x] = b1a[threadIdx.x];
    __syncthreads();
    int e = blockIdx.x * 256 + threadIdx.x;
    if (e >= E) return;
    int row = ei[e];
    int col = ei[NE + e];
    float h[64];
    #pragma unroll
    for (int j = 0; j < 64; ++j) h[j] = sb[j];
    const float4* xrow = (const float4*)(x + (size_t)col * 32);
    #pragma unroll
    for (int k4 = 0; k4 < 8; ++k4) {
        float4 v = xrow[k4];
        float vv[4] = {v.x, v.y, v.z, v.w};
        #pragma unroll
        for (int c = 0; c < 4; ++c) {
            float val = vv[c];
            const float4* wr = (const float4*)&sWA[(k4 * 4 + c) * 64];
            #pragma unroll
            for (int j4 = 0; j4 < 16; ++j4) {
                float4 w = wr[j4];
                h[j4 * 4 + 0] += val * w.x; h[j4 * 4 + 1] += val * w.y;
                h[j4 * 4 + 2] += val * w.z; h[j4 * 4 + 3] += val * w.w;
            }
        }
    }
    const float4* earow = (const float4*)(ea + (size_t)e * 32);
    #pragma unroll
    for (int k4 = 0; k4 < 8; ++k4) {
        float4 v = earow[k4];
        float vv[4] = {v.x, v.y, v.z, v.w};
        #pragma unroll
        for (int c = 0; c < 4; ++c) {
            float val = vv[c];
            const float4* wr = (const float4*)&sWB[(k4 * 4 + c) * 64];
            #pragma unroll
            for (int j4 = 0; j4 < 16; ++j4) {
                float4 w = wr[j4];
                h[j4 * 4 + 0] += val * w.x; h[j4 * 4 + 1] += val * w.y;
                h[j4 * 4 + 2] += val * w.z; h[j4 * 4 + 3] += val * w.w;
            }
        }
    }
    float* srow = Sacc + (size_t)row * 64;
    #pragma unroll
    for (int j = 0; j < 64; ++j) atomicAdd(&srow[j], fmaxf(h[j], 0.f));
}

extern "C" void kernel_launch(void* const* d_in, const int* in_sizes, int n_in,
                              void* d_out, int out_size, void* d_ws, size_t ws_size,
                              hipStream_t stream) {
    const float* x   = (const float*)d_in[0];
    const int*   ei  = (const int*)d_in[1];
    const float* ea  = (const float*)d_in[2];
    const float* W1a = (const float*)d_in[5];
    const float* b1a = (const float*)d_in[6];
    const float* W1b = (const float*)d_in[7];
    const float* b1b = (const float*)d_in[8];
    const float* W2a = (const float*)d_in[9];
    const float* b2a = (const float*)d_in[10];
    const float* W2b = (const float*)d_in[11];
    const float* b2b = (const float*)d_in[12];
    float* out = (float*)d_out;

    // workspace layout (~244 MB)
    char* p = (char*)d_ws;
    int* deg        = (int*)p;        p += (size_t)NN * 4;
    int* offs       = (int*)p;        p += (size_t)NN * 4;
    int* bsums      = (int*)p;        p += 2048;
    float* Wc       = (float*)p;      p += 4096 * 4;
    float* bc       = (float*)p;      p += 64 * 4;
    uint4* wpack    = (uint4*)p;      p += 512 * 16;
    int* pos        = (int*)p;        p += (size_t)NE * 4;        // rank -> final slot (in place)
    uint32* xbw     = (uint32*)p;     p += (size_t)NN * 16 * 4;   // [NN][32] bf16
    float* Sacc     = (float*)p;      p += (size_t)NN * 64 * 4;
    size_t off_g    = (size_t)(p - (char*)d_ws);
    uint32* g       = (uint32*)p;     // [NE][64] bf16 = 128B rows
    size_t need     = off_g + (size_t)NE * 128;

    dim3 blk(256);

    if (ws_size >= need) {
        hipMemsetAsync(deg, 0, (size_t)NN * 4, stream);
        hipLaunchKernelGGL(k_hist_prep, dim3(HB + PB), blk, 0, stream,
                           ei, deg, pos, W1b, b1b, W2a, W1a, x, Wc, bc, wpack, xbw, 1);
        hipLaunchKernelGGL(k_scan1, dim3(NB), blk, 0, stream, deg, offs, bsums, NN);
        hipLaunchKernelGGL(k_scan2, dim3(1), dim3(512), 0, stream, bsums, NB);
        hipLaunchKernelGGL(k_pos, dim3((NE + 255) / 256), blk, 0, stream, ei, offs, bsums, pos, NE);
        hipLaunchKernelGGL(k_edge_mfma, dim3(NE / (64 * TPW)), blk, 0, stream,
                           ei, ea, xbw, wpack, b1a, pos, g);
        hipLaunchKernelGGL(k_seg_c, dim3((NN + 3) / 4), blk, 0, stream, deg, offs, bsums, g, Sacc);
        hipLaunchKernelGGL(k_node, dim3(NB), blk, 0, stream,
                           x, Sacc, deg, Wc, bc, W2a, b2a, W2b, b2b, out, NN);
    } else {
        // fallback: fp32 atomic scatter (natural channel order)
        hipMemsetAsync(deg, 0, (size_t)NN * 4, stream);
        hipMemsetAsync(Sacc, 0, (size_t)NN * 64 * 4, stream);
        hipLaunchKernelGGL(k_hist_prep, dim3(HB + PB), blk, 0, stream,
                           ei, deg, pos, W1b, b1b, W2a, W1a, x, Wc, bc, wpack, xbw, 0);
        hipLaunchKernelGGL(k_edge_atom, dim3((NE + 255) / 256), blk, 0, stream,
                           x, ei, ea, W1a, b1a, Sacc, NE);
        hipLaunchKernelGGL(k_node, dim3(NB), blk, 0, stream,
                           x, Sacc, deg, Wc, bc, W2a, b2a, W2b, b2b, out, NN);
    }
}